// Round 4
// baseline (205.834 us; speedup 1.0000x reference)
//
#include <hip/hip_runtime.h>
#include <hip/hip_bf16.h>
#include <stdint.h>

typedef unsigned short u16;
typedef __bf16 bf16x8 __attribute__((ext_vector_type(8)));
typedef float f32x4 __attribute__((ext_vector_type(4)));

#define MFMA16(a, b, c) __builtin_amdgcn_mfma_f32_16x16x32_bf16((a), (b), (c), 0, 0, 0)

#define GLOAD16(g, l)                                                        \
  __builtin_amdgcn_global_load_lds(                                          \
      (const __attribute__((address_space(1))) void*)(g),                    \
      (__attribute__((address_space(3))) void*)(l), 16, 0, 0)

#define SBAR() __builtin_amdgcn_s_barrier()
#define SCHEDBAR() __builtin_amdgcn_sched_barrier(0)

static __device__ __forceinline__ u16 f2bf(float f) {
  union { float f; uint32_t u; } v;
  v.f = f;
  uint32_t u = v.u;
  return (u16)((u + 0x7FFFu + ((u >> 16) & 1u)) >> 16);  // RNE
}

// ---- workspace layout (u16 elements) ----
#define FEATT_ELEMS (8u * 98u * 98u * 256u)   // [b][h+1][w+1][c] bf16, zero halo
#define W1T_OFF     FEATT_ELEMS               // [oc][tap][cin] bf16: 256*2304
#define W1T_ELEMS   (256u * 2304u)
#define W2B_OFF     (W1T_OFF + W1T_ELEMS)     // [576][256] bf16

// ---------------- halo zeroing (halo is 1.6MB) ------------
__global__ __launch_bounds__(256) void halo_zero(u16* __restrict__ featT) {
  int tid = blockIdx.x * 256 + threadIdx.x;  // 8 * 388 * 32 = 99328 threads
  int b = tid / (388 * 32);
  int rem = tid % (388 * 32);
  int pos = rem >> 5, v = rem & 31;
  int h, w;
  if (pos < 98) { h = 0; w = pos; }
  else if (pos < 196) { h = 97; w = pos - 98; }
  else if (pos < 292) { h = pos - 196 + 1; w = 0; }
  else { h = pos - 292 + 1; w = 97; }
  uint4* dst = (uint4*)(featT + (size_t)((b * 98 + h) * 98 + w) * 256 + v * 8);
  *dst = make_uint4(0, 0, 0, 0);
}

// ---------------- prep: feat NCHW f32 -> featT [b][h+1][w+1][c] bf16 -------------
__global__ __launch_bounds__(256) void prep_featT(const float* __restrict__ feat,
                                                  u16* __restrict__ featT) {
  const int pt = blockIdx.x, ct = blockIdx.y, b = blockIdx.z;
  const int p0 = pt * 64, c0 = ct * 64;
  __shared__ float tile[64][65];
  const int t = threadIdx.x;
  const int pj = t & 63, ci0 = t >> 6;
#pragma unroll
  for (int r = 0; r < 16; ++r) {
    int ci = r * 4 + ci0;
    tile[ci][pj] = feat[(b * 256 + c0 + ci) * 9216 + p0 + pj];
  }
  __syncthreads();
  const int pl = t >> 2, cc0 = (t & 3) * 16;
  const int pix = p0 + pl;
  const int h = pix / 96, w = pix % 96;
  uint32_t u[8];
#pragma unroll
  for (int i = 0; i < 8; ++i) {
    u16 lo = f2bf(tile[cc0 + 2 * i][pl]);
    u16 hi = f2bf(tile[cc0 + 2 * i + 1][pl]);
    u[i] = (uint32_t)lo | ((uint32_t)hi << 16);
  }
  uint4* dst = (uint4*)(featT + (size_t)((b * 98 + h + 1) * 98 + (w + 1)) * 256 + c0 + cc0);
  dst[0] = make_uint4(u[0], u[1], u[2], u[3]);
  dst[1] = make_uint4(u[4], u[5], u[6], u[7]);
}

// ---------------- prep: weights -> bf16 (w1 reordered to [oc][tap][cin]) ---------
__global__ __launch_bounds__(256) void prep_w(const float* __restrict__ w1,
                                              const float* __restrict__ w2,
                                              u16* __restrict__ w1t,
                                              u16* __restrict__ w2b) {
  int i = blockIdx.x * 256 + threadIdx.x;
  if (i < 589824) {
    int oc = i / 2304, r = i % 2304;
    int tap = r >> 8, cin = r & 255;
    w1t[i] = f2bf(w1[(oc * 256 + cin) * 9 + tap]);
  } else {
    int j = i - 589824;
    if (j < 147456) w2b[j] = f2bf(w2[j]);
  }
}

// =================== FUSED: conv3x3+relu -> 1x1 -> softmax -> combine ===========
// Tile = one image row (96 pixels), full N=256. 768 blocks = 3/CU exact rounds.
// Phase A: GEMM M=96,N=256,K=2304; 2-deep pipeline, COUNTED vmcnt (T3+T4),
//          raw s_barriers, setprio (T5). Per-wave stage loads = 6/5 -> vmcnt(5).
// Phase C: mask GEMM (N_virt=576) + softmax + flow-combine, counted vmcnt(4).
__global__ __launch_bounds__(512, 2) void fused(const u16* __restrict__ featT,
                                                const u16* __restrict__ w1t,
                                                const float* __restrict__ b1,
                                                const u16* __restrict__ w2b,
                                                const float* __restrict__ b2,
                                                const float* __restrict__ flow,
                                                float* __restrict__ out) {
  // [0,45056): phase A dbuf (2 x (sA 6144 + sB 16384))
  // [0,24576): sX handoff (96x256)    [24576,61440): phase C B dbuf (2 x 18432)
  __shared__ __align__(16) u16 smem[61440];      // 120 KB
  __shared__ float sFlow[2][9][96];              // 6.75 KB
  __shared__ float sb1[256];
  __shared__ float sb2[576];

  const int t = threadIdx.x;
  const int wave = t >> 6, lane = t & 63;
  const int bid = blockIdx.x;
  const int mt = (bid & 7) * 96 + (bid >> 3);    // bijective XCD swizzle (768%8==0)
  const int b = mt / 96;
  const int h0 = mt % 96;                        // this block = image row h0

  if (t < 256) sb1[t] = b1[t];
  for (int i = t; i < 576; i += 512) sb2[i] = b2[i];
  for (int i = t; i < 1728; i += 512) {
    int c = i / 864, rem = i % 864;
    int k = rem / 96, p = rem % 96;
    int hh = h0 + k / 3 - 1, ww = p + k % 3 - 1;
    float v = 0.f;
    if (hh >= 0 && hh < 96 && ww >= 0 && ww < 96)
      v = flow[((b * 2 + c) * 96 + hh) * 96 + ww];
    sFlow[c][k][p] = v;
  }

  // ---- phase A staging bases (source pre-swizzled chunks) ----
  const u16* aBase[2];
#pragma unroll
  for (int r = 0; r < 2; ++r) {
    int row = (r * 8 + wave) * 8 + (lane >> 3);  // w-coordinate, 0..95 (wr<12 valid)
    int chunk = (lane & 7) ^ (row & 7);
    aBase[r] = featT + ((size_t)(b * 98 + h0 + 1) * 98 + (row + 1)) * 256 + chunk * 8;
  }
  const u16* bBase[4];
#pragma unroll
  for (int r = 0; r < 4; ++r) {
    int row = (r * 8 + wave) * 8 + (lane >> 3);  // oc, 0..255
    int chunk = (lane & 7) ^ (row & 7);
    bBase[r] = w1t + (size_t)row * 2304 + chunk * 8;
  }

  auto stageA = [&](int kt, int bufi) {
    int tap = kt >> 2;
    int dh = tap / 3 - 1, dw = tap % 3 - 1;
    int aoff = (dh * 98 + dw) * 256 + (kt & 3) * 64;
    int boff = kt * 64;
    u16* base = &smem[bufi * 22528];
#pragma unroll
    for (int r = 0; r < 2; ++r) {
      int wr = r * 8 + wave;
      if (wr < 12) GLOAD16(aBase[r] + aoff, base + wr * 512);
    }
#pragma unroll
    for (int r = 0; r < 4; ++r)
      GLOAD16(bBase[r] + boff, base + 6144 + (r * 8 + wave) * 512);
  };

  const int wm = wave >> 2, wn = wave & 3;
  int aoffs[3][2], boffs[4][2];
#pragma unroll
  for (int ki = 0; ki < 2; ++ki) {
    int kc = ki * 4 + (lane >> 4);
#pragma unroll
    for (int m = 0; m < 3; ++m) {
      int rowa = wm * 48 + m * 16 + (lane & 15);
      aoffs[m][ki] = rowa * 64 + ((kc ^ (rowa & 7)) * 8);
    }
#pragma unroll
    for (int n = 0; n < 4; ++n) {
      int rowb = wn * 64 + n * 16 + (lane & 15);
      boffs[n][ki] = rowb * 64 + ((kc ^ (rowb & 7)) * 8);
    }
  }

  f32x4 acc[3][4];
#pragma unroll
  for (int m = 0; m < 3; ++m)
#pragma unroll
    for (int n = 0; n < 4; ++n) acc[m][n] = f32x4{0.f, 0.f, 0.f, 0.f};

  auto computeA = [&](int bufi) {
    const u16* base = &smem[bufi * 22528];
    __builtin_amdgcn_s_setprio(1);
#pragma unroll
    for (int ki = 0; ki < 2; ++ki) {
      bf16x8 av[3], bv[4];
#pragma unroll
      for (int m = 0; m < 3; ++m) av[m] = *(const bf16x8*)&base[aoffs[m][ki]];
#pragma unroll
      for (int n = 0; n < 4; ++n) bv[n] = *(const bf16x8*)&base[6144 + boffs[n][ki]];
#pragma unroll
      for (int m = 0; m < 3; ++m)
#pragma unroll
        for (int n = 0; n < 4; ++n) acc[m][n] = MFMA16(av[m], bv[n], acc[m][n]);
    }
    __builtin_amdgcn_s_setprio(0);
  };

  // prologue barrier: drains prologue loads (clean vmcnt) + publishes sFlow/sb
  __syncthreads();
  stageA(0, 0);
  stageA(1, 1);

  for (int kt = 0; kt < 34; ++kt) {
    asm volatile("s_waitcnt vmcnt(5)" ::: "memory");  // own tile-kt loads landed
    SBAR();                                           // everyone's tile-kt landed
    SCHEDBAR();
    computeA(kt & 1);
    asm volatile("s_waitcnt lgkmcnt(0)" ::: "memory");
    SBAR();                                           // all reads of buf done
    SCHEDBAR();
    stageA(kt + 2, kt & 1);                           // overwrite consumed buf
  }
  // kt = 34
  asm volatile("s_waitcnt vmcnt(5)" ::: "memory");
  SBAR(); SCHEDBAR();
  computeA(0);
  asm volatile("s_waitcnt lgkmcnt(0)" ::: "memory");
  SBAR(); SCHEDBAR();
  // kt = 35
  asm volatile("s_waitcnt vmcnt(0)" ::: "memory");
  SBAR(); SCHEDBAR();
  computeA(1);
  __syncthreads();  // full drain: phase A done, bufs free for sX

  // ---- phase A epilogue: bias+relu -> sX[pix][oc] (chunk-swizzled) ----
  const int g4 = (lane >> 4) << 2;
#pragma unroll
  for (int m = 0; m < 3; ++m) {
    int pixr = wm * 48 + m * 16 + g4;
#pragma unroll
    for (int n = 0; n < 4; ++n) {
      int oc = wn * 64 + n * 16 + (lane & 15);
      float bias = sb1[oc];
      f32x4 v = acc[m][n];
#pragma unroll
      for (int j = 0; j < 4; ++j) {
        int pix = pixr + j;
        float val = v[j] + bias;
        val = val > 0.f ? val : 0.f;
        smem[pix * 256 + (((oc >> 3) ^ (pix & 7)) * 8) + (oc & 7)] = f2bf(val);
      }
    }
  }
  __syncthreads();  // sX complete; vmcnt clean

  // ---- phase C: B2 staging + A-frag extraction ----
  auto stageB = [&](int step, int bufi) {
    int cI = step >> 1, kh = step & 1;
    u16* base = &smem[24576 + bufi * 18432];
#pragma unroll
    for (int r = 0; r < 5; ++r) {
      int wr = r * 8 + wave;  // wave-uniform condition
      if (wr < 36) {
        int row = wr * 4 + (lane >> 4);  // virtual n, 0..143
        int chan = (row >> 4) * 64 + cI * 16 + (row & 15);
        int c = lane & 15;
        const u16* src = w2b + (size_t)chan * 256 + kh * 128 + ((c ^ (row & 15)) * 8);
        GLOAD16(src, base + wr * 512);
      }
    }
  };

  stageB(0, 0);  // per-wave loads: 5 (waves 0-3) / 4 (waves 4-7)
  stageB(1, 1);
  bf16x8 areg[8];
  const int pixl = wave * 16 + (lane & 15);  // valid for wave<6
  if (wave < 6) {
#pragma unroll
    for (int s = 0; s < 8; ++s) {
      int kc = s * 4 + (lane >> 4);  // oc chunk 0..31
      areg[s] = *(const bf16x8*)&smem[pixl * 256 + ((kc ^ (pixl & 7)) * 8)];
    }
  }

  f32x4 acc2[9];
#pragma unroll
  for (int step = 0; step < 8; ++step) {
    if (step == 7) asm volatile("s_waitcnt vmcnt(0)" ::: "memory");
    else           asm volatile("s_waitcnt vmcnt(4)" ::: "memory");
    SBAR();
    SCHEDBAR();
    const int kh = step & 1, cI = step >> 1;
    const int bufc = step & 1;
    if (wave < 6) {
      if (kh == 0) {
#pragma unroll
        for (int nf = 0; nf < 9; ++nf) acc2[nf] = f32x4{0.f, 0.f, 0.f, 0.f};
      }
      const u16* base = &smem[24576 + bufc * 18432];
      __builtin_amdgcn_s_setprio(1);
#pragma unroll
      for (int ki = 0; ki < 4; ++ki) {
        bf16x8 a = areg[kh * 4 + ki];
        int kc = ki * 4 + (lane >> 4);
#pragma unroll
        for (int nf = 0; nf < 9; ++nf) {
          int row = nf * 16 + (lane & 15);
          bf16x8 bv = *(const bf16x8*)&base[row * 128 + ((kc ^ (row & 15)) * 8)];
          acc2[nf] = MFMA16(a, bv, acc2[nf]);
        }
      }
      __builtin_amdgcn_s_setprio(0);
      if (kh == 1) {
        int pql = lane & 15;
        int p = cI * 2 + (pql >> 3), q = pql & 7;
#pragma unroll
        for (int j = 0; j < 4; ++j) {
          int pe = wave * 16 + g4 + j;  // w-coordinate, 0..95
          float v[9], mx = -3.0e38f;
#pragma unroll
          for (int nf = 0; nf < 9; ++nf) {
            v[nf] = acc2[nf][j] + sb2[nf * 64 + cI * 16 + pql];
            mx = fmaxf(mx, v[nf]);
          }
          float s = 0.f, fx = 0.f, fy = 0.f;
#pragma unroll
          for (int nf = 0; nf < 9; ++nf) {
            float e = __expf(v[nf] - mx);
            s += e;
            fx += e * sFlow[0][nf][pe];
            fy += e * sFlow[1][nf][pe];
          }
          float sc = 8.0f / s;
          size_t o0 = ((size_t)(b * 2 + 0) * 768 + h0 * 8 + p) * 768 + pe * 8 + q;
          size_t o1 = ((size_t)(b * 2 + 1) * 768 + h0 * 8 + p) * 768 + pe * 8 + q;
          out[o0] = fx * sc;
          out[o1] = fy * sc;
        }
      }
    }
    asm volatile("s_waitcnt lgkmcnt(0)" ::: "memory");
    SBAR();
    SCHEDBAR();
    if (step < 6) stageB(step + 2, step & 1);
  }
}

extern "C" void kernel_launch(void* const* d_in, const int* in_sizes, int n_in,
                              void* d_out, int out_size, void* d_ws, size_t ws_size,
                              hipStream_t stream) {
  const float* flow = (const float*)d_in[0];
  const float* feat = (const float*)d_in[1];
  const float* w1 = (const float*)d_in[2];
  const float* b1 = (const float*)d_in[3];
  const float* w2 = (const float*)d_in[4];
  const float* b2 = (const float*)d_in[5];
  float* out = (float*)d_out;
  u16* ws = (u16*)d_ws;
  u16* featT = ws;
  u16* w1t = ws + W1T_OFF;
  u16* w2b = ws + W2B_OFF;

  halo_zero<<<388, 256, 0, stream>>>(featT);
  prep_featT<<<dim3(144, 4, 8), 256, 0, stream>>>(feat, featT);
  prep_w<<<2880, 256, 0, stream>>>(w1, w2, w1t, w2b);
  fused<<<768, 512, 0, stream>>>(featT, w1t, b1, w2b, b2, flow, out);
}

// Round 6
// 194.544 us; speedup vs baseline: 1.0580x; 1.0580x over previous
//
#include <hip/hip_runtime.h>
#include <hip/hip_bf16.h>
#include <stdint.h>

typedef unsigned short u16;
typedef __bf16 bf16x8 __attribute__((ext_vector_type(8)));
typedef float f32x4 __attribute__((ext_vector_type(4)));

#define MFMA16(a, b, c) __builtin_amdgcn_mfma_f32_16x16x32_bf16((a), (b), (c), 0, 0, 0)

#define GLOAD16(g, l)                                                        \
  __builtin_amdgcn_global_load_lds(                                          \
      (const __attribute__((address_space(1))) void*)(g),                    \
      (__attribute__((address_space(3))) void*)(l), 16, 0, 0)

#define SBAR() __builtin_amdgcn_s_barrier()
#define SCHEDBAR() __builtin_amdgcn_sched_barrier(0)
#define VMCNT(n) asm volatile("s_waitcnt vmcnt(" #n ")" ::: "memory")
#define LGKM0() asm volatile("s_waitcnt lgkmcnt(0)" ::: "memory")

static __device__ __forceinline__ u16 f2bf(float f) {
  union { float f; uint32_t u; } v;
  v.f = f;
  uint32_t u = v.u;
  return (u16)((u + 0x7FFFu + ((u >> 16) & 1u)) >> 16);  // RNE
}
static __device__ __forceinline__ float bf2f(u16 u) {
  union { uint32_t u; float f; } v;
  v.u = ((uint32_t)u) << 16;
  return v.f;
}

// ---- workspace layout (u16 elements) ----
#define FEATT_ELEMS (8u * 98u * 98u * 256u)   // [b][h+1][w+1][c] bf16, zero halo
#define W1T_OFF     FEATT_ELEMS               // [oc][tap][cin] bf16: 256*2304
#define W1T_ELEMS   (256u * 2304u)
#define W2B_OFF     (W1T_OFF + W1T_ELEMS)     // [576][256] bf16

// ---------------- halo zeroing (halo is 1.6MB) ------------
__global__ __launch_bounds__(256) void halo_zero(u16* __restrict__ featT) {
  int tid = blockIdx.x * 256 + threadIdx.x;  // 8 * 388 * 32 = 99328 threads
  int b = tid / (388 * 32);
  int rem = tid % (388 * 32);
  int pos = rem >> 5, v = rem & 31;
  int h, w;
  if (pos < 98) { h = 0; w = pos; }
  else if (pos < 196) { h = 97; w = pos - 98; }
  else if (pos < 292) { h = pos - 196 + 1; w = 0; }
  else { h = pos - 292 + 1; w = 97; }
  uint4* dst = (uint4*)(featT + (size_t)((b * 98 + h) * 98 + w) * 256 + v * 8);
  *dst = make_uint4(0, 0, 0, 0);
}

// ---------------- prep: feat NCHW f32 -> featT [b][h+1][w+1][c] bf16 -------------
__global__ __launch_bounds__(256) void prep_featT(const float* __restrict__ feat,
                                                  u16* __restrict__ featT) {
  const int pt = blockIdx.x, ct = blockIdx.y, b = blockIdx.z;
  const int p0 = pt * 64, c0 = ct * 64;
  __shared__ float tile[64][65];
  const int t = threadIdx.x;
  const int pj = t & 63, ci0 = t >> 6;
#pragma unroll
  for (int r = 0; r < 16; ++r) {
    int ci = r * 4 + ci0;
    tile[ci][pj] = feat[(b * 256 + c0 + ci) * 9216 + p0 + pj];
  }
  __syncthreads();
  const int pl = t >> 2, cc0 = (t & 3) * 16;
  const int pix = p0 + pl;
  const int h = pix / 96, w = pix % 96;
  uint32_t u[8];
#pragma unroll
  for (int i = 0; i < 8; ++i) {
    u16 lo = f2bf(tile[cc0 + 2 * i][pl]);
    u16 hi = f2bf(tile[cc0 + 2 * i + 1][pl]);
    u[i] = (uint32_t)lo | ((uint32_t)hi << 16);
  }
  uint4* dst = (uint4*)(featT + (size_t)((b * 98 + h + 1) * 98 + (w + 1)) * 256 + c0 + cc0);
  dst[0] = make_uint4(u[0], u[1], u[2], u[3]);
  dst[1] = make_uint4(u[4], u[5], u[6], u[7]);
}

// ---------------- prep: weights -> bf16 (w1 reordered to [oc][tap][cin]) ---------
__global__ __launch_bounds__(256) void prep_w(const float* __restrict__ w1,
                                              const float* __restrict__ w2,
                                              u16* __restrict__ w1t,
                                              u16* __restrict__ w2b) {
  int i = blockIdx.x * 256 + threadIdx.x;
  if (i < 589824) {
    int oc = i / 2304, r = i % 2304;
    int tap = r >> 8, cin = r & 255;
    w1t[i] = f2bf(w1[(oc * 256 + cin) * 9 + tap]);
  } else {
    int j = i - 589824;
    if (j < 147456) w2b[j] = f2bf(w2[j]);
  }
}

// =================== FUSED: conv3x3+relu -> 1x1 -> softmax -> combine ===========
// Block = 64 pixels (image-LOCAL ipl0 = (mt%144)*64), 256 threads (4 waves), BK=32.
// LDS 53.5 KB -> 3 blocks/CU. Counted-vmcnt 2-deep pipeline in both GEMM phases.
__global__ __launch_bounds__(256, 3) void fused(const u16* __restrict__ featT,
                                                const u16* __restrict__ w1t,
                                                const float* __restrict__ b1g,
                                                const u16* __restrict__ w2b,
                                                const float* __restrict__ b2g,
                                                const float* __restrict__ flow,
                                                float* __restrict__ out) {
  __shared__ __align__(16) u16 smem[26752];  // 53504 B

  const int t = threadIdx.x;
  const int wave = t >> 6, lane = t & 63;
  const int bid = blockIdx.x;
  const int mt = (bid & 7) * 144 + (bid >> 3);  // bijective XCD swizzle (1152%8==0)
  const int b = mt / 144;
  const int ipl0 = (mt % 144) * 64;  // image-LOCAL pixel base, 0..9152

  // ---- sFlow (bf16) fill: [2][9][64] at smem+25600 ----
  for (int i = t; i < 1152; i += 256) {
    int c = i / 576, rem = i % 576;
    int k = rem >> 6, p = rem & 63;
    int ip = ipl0 + p;           // image-local
    int h = ip / 96, w = ip % 96;
    int hh = h + k / 3 - 1, ww = w + k % 3 - 1;
    float v = 0.f;
    if (hh >= 0 && hh < 96 && ww >= 0 && ww < 96)
      v = flow[((b * 2 + c) * 96 + hh) * 96 + ww];
    smem[25600 + i] = f2bf(v);
  }

  // ---- phase A staging bases (chunk-XOR source pre-swizzle, sigma=(row>>1)&3) ----
  const int pA = wave * 16 + (lane >> 2);  // this lane's A row (block-local pixel)
  const u16* aSrc;
  {
    int ip = ipl0 + pA;          // image-local
    int h = ip / 96, w = ip % 96;
    int cs = (lane & 3) ^ ((pA >> 1) & 3);
    aSrc = featT + ((size_t)(b * 98 + h + 1) * 98 + (w + 1)) * 256 + cs * 8;
  }
  const u16* bSrc[4];
#pragma unroll
  for (int i = 0; i < 4; ++i) {
    int oc = (i * 4 + wave) * 16 + (lane >> 2);
    int cs = (lane & 3) ^ ((oc >> 1) & 3);
    bSrc[i] = w1t + (size_t)oc * 2304 + cs * 8;
  }

  auto stageA = [&](int kt, int bufi) {
    int tap = kt >> 3;
    int dh = tap / 3 - 1, dw = tap % 3 - 1;
    int aoff = (dh * 98 + dw) * 256 + (kt & 7) * 32;
    int boff = kt * 32;
    u16* db = &smem[bufi * 10240];
    GLOAD16(aSrc + aoff, db + wave * 512);
#pragma unroll
    for (int r = 0; r < 4; ++r)
      GLOAD16(bSrc[r] + boff, db + 2048 + (r * 4 + wave) * 512);
  };

  f32x4 acc[4][4];
#pragma unroll
  for (int m = 0; m < 4; ++m)
#pragma unroll
    for (int n = 0; n < 4; ++n) acc[m][n] = f32x4{0.f, 0.f, 0.f, 0.f};

  const int l15 = lane & 15, kc = lane >> 4;
  int aoffs[4], boffs[4];
#pragma unroll
  for (int m = 0; m < 4; ++m) {
    int r = m * 16 + l15;
    aoffs[m] = r * 32 + ((kc ^ ((r >> 1) & 3)) * 8);
  }
#pragma unroll
  for (int n = 0; n < 4; ++n) {
    int oc = wave * 64 + n * 16 + l15;
    boffs[n] = (64 + oc) * 32 + ((kc ^ ((oc >> 1) & 3)) * 8);
  }

  auto computeA = [&](int bufi) {
    const u16* base = &smem[bufi * 10240];
    __builtin_amdgcn_s_setprio(1);
    bf16x8 av[4], bv[4];
#pragma unroll
    for (int m = 0; m < 4; ++m) av[m] = *(const bf16x8*)&base[aoffs[m]];
#pragma unroll
    for (int n = 0; n < 4; ++n) bv[n] = *(const bf16x8*)&base[boffs[n]];
#pragma unroll
    for (int m = 0; m < 4; ++m)
#pragma unroll
      for (int n = 0; n < 4; ++n) acc[m][n] = MFMA16(av[m], bv[n], acc[m][n]);
    __builtin_amdgcn_s_setprio(0);
  };

  __syncthreads();  // drain sFlow loads (clean vmcnt) before staging
  stageA(0, 0);
  stageA(1, 1);

  for (int kt = 0; kt < 70; ++kt) {
    VMCNT(5);  // own stage(kt) loads (5) landed; stage(kt+1) still in flight
    SBAR(); SCHEDBAR();
    computeA(kt & 1);
    LGKM0();
    SBAR(); SCHEDBAR();
    stageA(kt + 2, kt & 1);
  }
  VMCNT(5); SBAR(); SCHEDBAR();
  computeA(0);
  LGKM0(); SBAR(); SCHEDBAR();
  VMCNT(0); SBAR(); SCHEDBAR();
  computeA(1);
  __syncthreads();  // phase A fully done; [0,20480) free for sX

  // ---- epilogue A: bias+relu -> sX[pix][256] (8-elem chunk XOR sigma=pix&7) ----
  const int g4 = kc << 2;
#pragma unroll
  for (int m = 0; m < 4; ++m) {
    int pixr = m * 16 + g4;
#pragma unroll
    for (int n = 0; n < 4; ++n) {
      int oc = wave * 64 + n * 16 + l15;
      float bias = b1g[oc];
      f32x4 v = acc[m][n];
#pragma unroll
      for (int j = 0; j < 4; ++j) {
        int pix = pixr + j;
        float val = v[j] + bias;
        val = val > 0.f ? val : 0.f;
        smem[pix * 256 + (((oc >> 3) ^ (pix & 7)) * 8) + (oc & 7)] = f2bf(val);
      }
    }
  }
  __syncthreads();  // sX complete; vmcnt clean

  // ---- phase C: B2 dbuf staging [16384,25600), areg from sX ----
  auto stageC = [&](int cI, int k8, int bufi) {
    u16* db = &smem[16384 + bufi * 4608];
#pragma unroll
    for (int i = 0; i < 3; ++i) {
      int g = i * 4 + wave;  // wave-uniform predicate
      if (g < 9) {
        int n = g * 16 + (lane >> 2);  // virtual n, 0..143
        int chan = (n >> 4) * 64 + cI * 16 + (n & 15);
        int cs = (lane & 3) ^ ((n >> 1) & 3);
        GLOAD16(w2b + (size_t)chan * 256 + k8 * 32 + cs * 8, db + g * 512);
      }
    }
  };

  stageC(0, 0, 0);
  stageC(0, 1, 1);

  bf16x8 areg[8];
  const int pixl = wave * 16 + l15;
#pragma unroll
  for (int s = 0; s < 8; ++s) {
    int kco = s * 4 + kc;  // oc chunk 0..31
    areg[s] = *(const bf16x8*)&smem[pixl * 256 + ((kco ^ (pixl & 7)) * 8)];
  }

  f32x4 acc2[9];
  for (int cI = 0; cI < 4; ++cI) {
#pragma unroll
    for (int k8 = 0; k8 < 8; ++k8) {
      if (cI == 3 && k8 == 7) { VMCNT(0); } else { VMCNT(2); }
      SBAR(); SCHEDBAR();
      if (k8 == 0) {
#pragma unroll
        for (int nf = 0; nf < 9; ++nf) acc2[nf] = f32x4{0.f, 0.f, 0.f, 0.f};
      }
      const u16* base = &smem[16384 + (k8 & 1) * 4608];
      bf16x8 a = areg[k8];  // static index
      __builtin_amdgcn_s_setprio(1);
#pragma unroll
      for (int nf = 0; nf < 9; ++nf) {
        int n = nf * 16 + l15;
        bf16x8 bv = *(const bf16x8*)&base[n * 32 + ((kc ^ ((n >> 1) & 3)) * 8)];
        acc2[nf] = MFMA16(a, bv, acc2[nf]);
      }
      __builtin_amdgcn_s_setprio(0);
      if (k8 == 7) {
        // softmax + flow-combine + pixel-shuffle store for this cI (16 pq)
        int pql = l15;
        int p = cI * 2 + (pql >> 3), q = pql & 7;
#pragma unroll
        for (int j = 0; j < 4; ++j) {
          int pe = wave * 16 + g4 + j;
          float v[9], mx = -3.0e38f;
#pragma unroll
          for (int nf = 0; nf < 9; ++nf) {
            v[nf] = acc2[nf][j] + b2g[nf * 64 + cI * 16 + pql];
            mx = fmaxf(mx, v[nf]);
          }
          float s = 0.f, fx = 0.f, fy = 0.f;
#pragma unroll
          for (int nf = 0; nf < 9; ++nf) {
            float e = __expf(v[nf] - mx);
            s += e;
            fx += e * bf2f(smem[25600 + nf * 64 + pe]);
            fy += e * bf2f(smem[25600 + 576 + nf * 64 + pe]);
          }
          float sc = 8.0f / s;
          int ip = ipl0 + pe;  // image-local
          int h = ip / 96, w = ip % 96;
          size_t o0 = ((size_t)(b * 2 + 0) * 768 + h * 8 + p) * 768 + w * 8 + q;
          size_t o1 = ((size_t)(b * 2 + 1) * 768 + h * 8 + p) * 768 + w * 8 + q;
          out[o0] = fx * sc;
          out[o1] = fy * sc;
        }
      }
      LGKM0();
      SBAR(); SCHEDBAR();
      if (!(cI == 3 && k8 >= 6)) stageC(cI + (k8 >= 6 ? 1 : 0), (k8 + 2) & 7, k8 & 1);
    }
  }
}

extern "C" void kernel_launch(void* const* d_in, const int* in_sizes, int n_in,
                              void* d_out, int out_size, void* d_ws, size_t ws_size,
                              hipStream_t stream) {
  const float* flow = (const float*)d_in[0];
  const float* feat = (const float*)d_in[1];
  const float* w1 = (const float*)d_in[2];
  const float* b1 = (const float*)d_in[3];
  const float* w2 = (const float*)d_in[4];
  const float* b2 = (const float*)d_in[5];
  float* out = (float*)d_out;
  u16* ws = (u16*)d_ws;
  u16* featT = ws;
  u16* w1t = ws + W1T_OFF;
  u16* w2b = ws + W2B_OFF;

  halo_zero<<<388, 256, 0, stream>>>(featT);
  prep_featT<<<dim3(144, 4, 8), 256, 0, stream>>>(feat, featT);
  prep_w<<<2880, 256, 0, stream>>>(w1, w2, w1t, w2b);
  fused<<<1152, 256, 0, stream>>>(featT, w1t, b1, w2b, b2, flow, out);
}